// Round 22
// baseline (980.263 us; speedup 1.0000x reference)
//
#include <hip/hip_runtime.h>
#include <hip/hip_cooperative_groups.h>
#include <math.h>

namespace cg = cooperative_groups;

#define BB 16
#define NN 25200
#define NCLS 80
#define TOPK 1000
#define MAXDET 100
#define CAND_CAP 2048
#define RANKS 1024
#define HBINS 1024
#define HBASE 0xBD00u
#define BPI_C 99  // blocks/img for compact: ceil(25200/256)
static constexpr float NEGV = -1000000000.0f;
static constexpr float IMGSZ = 640.0f;

struct Meta {
  unsigned b1p;
  unsigned b1c;
  unsigned b1;
  unsigned n_true;
  unsigned cnt;
  unsigned pad0, pad1, pad2;
};

// ---- workspace layout (shared by mega + fallback paths) ----
#define HISTP_OFF 0
#define HISTS_OFF 65536
#define META_OFF 131072
#define ZERO_BYTES 132096  // histp + hists + meta
#define KEYS_OFF 132096
#define ARR_BYTES ((size_t)BB * NN * 4)
#define CCS_OFF (KEYS_OFF + ARR_BYTES)
#define PREDS_OFF (CCS_OFF + ARR_BYTES)
#define PKEY_OFF (PREDS_OFF + ARR_BYTES)
#define CAND_OFF (PKEY_OFF + ARR_BYTES)
#define CAND_BYTES ((size_t)9 * BB * CAND_CAP * 4)
#define BOXR_OFF (CAND_OFF + CAND_BYTES)
#define BOXR_BYTES ((size_t)5 * BB * RANKS * 4)
#define PAYR_OFF (BOXR_OFF + BOXR_BYTES)
#define PAYR_BYTES ((size_t)2 * BB * RANKS * 16)
#define MAT_OFF (PAYR_OFF + PAYR_BYTES)

__device__ __forceinline__ unsigned flipKey(float f) {
  unsigned u = __float_as_uint(f);
  return (u & 0x80000000u) ? ~u : (u | 0x80000000u);
}
__device__ __forceinline__ float unflipKey(unsigned k) {
  unsigned u = (k & 0x80000000u) ? (k & 0x7FFFFFFFu) : ~k;
  return __uint_as_float(u);
}

#define UMAX_DPP(VAR, CTRL)                                                                   \
  {                                                                                           \
    unsigned _o = (unsigned)__builtin_amdgcn_update_dpp(0, (int)(VAR), CTRL, 0xF, 0xF, true); \
    if (_o > (VAR)) (VAR) = _o;                                                               \
  }

// ---- decode helper (shared) ----
__device__ __forceinline__ void decode_store(const float* __restrict__ regs,
                                             const float* __restrict__ anchors, int img, int i,
                                             float cc, float cp, float sc, unsigned pos,
                                             float* __restrict__ cand) {
  const size_t S2 = (size_t)BB * CAND_CAP;
  size_t g = (size_t)img * NN + (size_t)i;
  const float* r = regs + g * 5;
  float d0 = r[0], d1 = r[1], d2 = r[2], d3 = r[3], obj = r[4];
  const float* a = anchors + (size_t)i * 4;
  float ax1 = a[0], ay1 = a[1], ax2 = a[2], ay2 = a[3];
  float aw = ax2 - ax1, ah = ay2 - ay1;
  float acx = (ax1 + ax2) * 0.5f, acy = (ay1 + ay2) * 0.5f;
  float cx = acx + d0 * aw, cy = acy + d1 * ah;
  float w = aw * expf(d2), h = ah * expf(d3);
  float hw = 0.5f * w, hh = 0.5f * h;
  float x1 = fminf(fmaxf(cx - hw, 0.0f), IMGSZ);
  float y1 = fminf(fmaxf(cy - hh, 0.0f), IMGSZ);
  float x2 = fminf(fmaxf(cx + hw, 0.0f), IMGSZ);
  float y2 = fminf(fmaxf(cy + hh, 0.0f), IMGSZ);
  size_t o = (size_t)img * CAND_CAP + pos;
  cand[0 * S2 + o] = x1;
  cand[1 * S2 + o] = y1;
  cand[2 * S2 + o] = x2;
  cand[3 * S2 + o] = y2;
  cand[4 * S2 + o] = obj;
  cand[5 * S2 + o] = cc;
  cand[6 * S2 + o] = cp;
  cand[7 * S2 + o] = sc;
  reinterpret_cast<unsigned*>(cand + 8 * S2)[o] = (unsigned)i;
}

// ======================= MEGA (cooperative) =======================
struct __align__(16) SMem {
  union {
    struct { unsigned part[256]; unsigned sfx[256]; int s_sel; unsigned s_cum; } scan;
    unsigned long long kk[CAND_CAP];                                       // 16 KB
    struct { float sx1[RANKS], sy1[RANKS], sx2[RANKS], sy2[RANKS], sar[RANKS]; } mtx;  // 20 KB
    struct { unsigned wins[MAXDET]; float lout[MAXDET * 7]; } s2;
  };
};

__device__ void ph_scan(SMem& sm, const unsigned* __restrict__ hist, Meta* __restrict__ meta,
                        int mode) {
  int t = threadIdx.x;
  for (int vb = blockIdx.x; vb < BB; vb += gridDim.x) {
    int img = vb;
    const unsigned* h = hist + (size_t)img * HBINS;
    uint4 mine = reinterpret_cast<const uint4*>(h)[t];
    unsigned s = mine.x + mine.y + mine.z + mine.w;
    if (t == 0) { sm.scan.s_sel = -1; sm.scan.s_cum = 0; }
    sm.scan.part[t] = s;
    sm.scan.sfx[t] = s;
    __syncthreads();
    for (int d = 1; d < 256; d <<= 1) {
      unsigned v = (t + d < 256) ? sm.scan.sfx[t + d] : 0u;
      __syncthreads();
      sm.scan.sfx[t] += v;
      __syncthreads();
    }
    {
      unsigned incl = sm.scan.sfx[t];
      unsigned excl = incl - sm.scan.part[t];
      if (incl >= (unsigned)TOPK && excl < (unsigned)TOPK) { sm.scan.s_sel = t; sm.scan.s_cum = excl; }
    }
    __syncthreads();
    unsigned total = sm.scan.sfx[0];
    if (total < (unsigned)TOPK) {
      if (t == 0) {
        if (mode == 0) meta[img].b1p = HBASE + 1;
        else if (mode == 1) meta[img].b1c = HBASE + 1;
        else { meta[img].b1 = HBASE + 1; meta[img].n_true = total; }
      }
    } else if (t == sm.scan.s_sel) {
      unsigned cum = sm.scan.s_cum;
      unsigned vals[4] = {mine.x, mine.y, mine.z, mine.w};
      int sel = 0;
      unsigned c_ge = 0;
      for (int j = 3; j >= 0; --j) {
        if (cum + vals[j] >= (unsigned)TOPK) { sel = j; c_ge = cum + vals[j]; break; }
        cum += vals[j];
      }
      unsigned bin = HBASE + (unsigned)(4 * t + sel);
      if (mode == 0) meta[img].b1p = bin;
      else if (mode == 1) meta[img].b1c = bin;
      else {
        meta[img].b1 = bin;
        meta[img].n_true = (c_ge > (unsigned)TOPK) ? (unsigned)TOPK : c_ge;
      }
    }
    __syncthreads();  // LDS reuse across vb
  }
}

__device__ void ph_cand(const float* __restrict__ regs, const float* __restrict__ clses,
                        const unsigned* __restrict__ pkey, const Meta* __restrict__ meta,
                        unsigned* __restrict__ keys, float* __restrict__ ccs,
                        int* __restrict__ preds, unsigned* __restrict__ hists, int mode) {
  int stride = gridDim.x * 256;
  for (int g = blockIdx.x * 256 + threadIdx.x; g < BB * NN; g += stride) {
    int img = g / NN;
    unsigned pk = pkey[g];
    unsigned pk16 = pk >> 16;
    unsigned lo = (mode == 0) ? meta[img].b1p : meta[img].b1c;
    unsigned hi = (mode == 0) ? 0x10000u : meta[img].b1p;
    if (pk16 < lo || pk16 >= hi) {
      if (mode == 0) keys[g] = 0u;
      continue;
    }
    const float4* r4 = reinterpret_cast<const float4*>(clses + (size_t)g * NCLS);
    float best = -1.0f;
    int bi = 0;
#pragma unroll
    for (int f = 0; f < 20; ++f) {
      float4 v = r4[f];
      int b0 = f * 4;
      if (v.x > best) { best = v.x; bi = b0 + 0; }
      if (v.y > best) { best = v.y; bi = b0 + 1; }
      if (v.z > best) { best = v.z; bi = b0 + 2; }
      if (v.w > best) { best = v.w; bi = b0 + 3; }
    }
    float pobj = unflipKey(pk);
    float sc = pobj * best;
    bool pass = (sc >= 0.05f);
    unsigned key = flipKey(pass ? sc : NEGV);
    keys[g] = key;
    ccs[g] = best;
    preds[g] = bi;
    if (pass) atomicAdd(&hists[(size_t)img * HBINS + ((key >> 16) - HBASE)], 1u);
  }
}

__device__ void ph_compact(const float* __restrict__ regs, const float* __restrict__ anchors,
                           const unsigned* __restrict__ keys, const float* __restrict__ ccs,
                           const int* __restrict__ preds, Meta* __restrict__ meta,
                           float* __restrict__ cand) {
  int lane = threadIdx.x & 63;
  unsigned long long lt = (1ull << lane) - 1ull;
  for (int vb = blockIdx.x; vb < BB * BPI_C; vb += gridDim.x) {
    int img = vb / BPI_C;
    int i = (vb % BPI_C) * 256 + threadIdx.x;
    bool act = (i < NN);
    unsigned key = 0u;
    size_t g = 0;
    if (act) {
      g = (size_t)img * NN + (size_t)i;
      key = keys[g];
    }
    bool take = act && ((key >> 16) >= meta[img].b1);
    unsigned long long mA = __ballot(take);
    if (take) {
      int leader = __builtin_ctzll(mA);
      unsigned base = 0;
      if (lane == leader) base = atomicAdd(&meta[img].cnt, (unsigned)__popcll(mA));
      base = __shfl(base, leader);
      unsigned pos = base + (unsigned)__popcll(mA & lt);
      if (pos < CAND_CAP)
        decode_store(regs, anchors, img, i, ccs[g], (float)preds[g], unflipKey(key), pos, cand);
    }
  }
}

__device__ void ph_rank(SMem& sm, const float* __restrict__ cand, const Meta* __restrict__ meta,
                        float* __restrict__ boxr, float4* __restrict__ payr0,
                        float4* __restrict__ payr1) {
  const size_t S2 = (size_t)BB * CAND_CAP;
  const int NR = BB * RANKS;
  int tid = threadIdx.x;
  for (int vb = blockIdx.x; vb < BB * 32; vb += gridDim.x) {
    int img = vb >> 5;
    int part = vb & 31;
    unsigned nload = meta[img].cnt;
    if (nload > CAND_CAP) nload = CAND_CAP;
    for (int i = tid; i < CAND_CAP; i += 256) {
      unsigned long long kv = 0ull;
      if (i < (int)nload) {
        float sc = cand[7 * S2 + (size_t)img * CAND_CAP + i];
        unsigned ai = reinterpret_cast<const unsigned*>(cand + 8 * S2)[(size_t)img * CAND_CAP + i];
        kv = ((unsigned long long)flipKey(sc) << 16) |
             (unsigned long long)((0x7FFFu - ai) & 0xFFFFu);
      }
      sm.kk[i] = kv;
    }
    __syncthreads();
    int slot = part * 64 + (tid >> 2);
    int qtr = tid & 3;
    unsigned long long myk = sm.kk[slot];
    unsigned rank = 0;
    for (int q = qtr * 512; q < qtr * 512 + 512; ++q) rank += (sm.kk[q] > myk) ? 1u : 0u;
    rank += (unsigned)__builtin_amdgcn_update_dpp(0, (int)rank, 0xB1, 0xF, 0xF, true);
    rank += (unsigned)__builtin_amdgcn_update_dpp(0, (int)rank, 0x4E, 0xF, 0xF, true);
    if (qtr == 0 && slot < (int)nload && rank < RANKS) {
      size_t o = (size_t)img * CAND_CAP + slot;
      float x1 = cand[0 * S2 + o], y1 = cand[1 * S2 + o];
      float x2 = cand[2 * S2 + o], y2 = cand[3 * S2 + o];
      float obj = cand[4 * S2 + o], cc = cand[5 * S2 + o];
      float cp = cand[6 * S2 + o], sc = cand[7 * S2 + o];
      float offv = cp * 4096.0f;
      float a1 = x1 + offv, b1v = y1 + offv, a2 = x2 + offv, b2v = y2 + offv;
      size_t ro = (size_t)img * RANKS + rank;
      boxr[0 * NR + ro] = a1;
      boxr[1 * NR + ro] = b1v;
      boxr[2 * NR + ro] = a2;
      boxr[3 * NR + ro] = b2v;
      boxr[4 * NR + ro] = (a2 - a1) * (b2v - b1v);
      payr0[ro] = make_float4(x1, y1, x2, y2);
      payr1[ro] = make_float4(obj, cc, cp, sc);
    }
    __syncthreads();  // LDS reuse across vb
  }
}

__device__ void ph_matrix(SMem& sm, const float* __restrict__ boxr, const Meta* __restrict__ meta,
                          unsigned long long* __restrict__ mat) {
  const int NR = BB * RANKS;
  int tid = threadIdx.x, lane = tid & 63, wid = tid >> 6;
  for (int vb = blockIdx.x; vb < BB * 64; vb += gridDim.x) {
    int img = vb >> 6;
    int part = vb & 63;
    for (int i = tid; i < RANKS; i += 256) {
      int g = img * RANKS + i;
      sm.mtx.sx1[i] = boxr[0 * NR + g];
      sm.mtx.sy1[i] = boxr[1 * NR + g];
      sm.mtx.sx2[i] = boxr[2 * NR + g];
      sm.mtx.sy2[i] = boxr[3 * NR + g];
      sm.mtx.sar[i] = boxr[4 * NR + g];
    }
    unsigned n = meta[img].n_true;
    __syncthreads();
#pragma unroll
    for (int rr = 0; rr < 4; ++rr) {
      int r = part * 16 + wid * 4 + rr;
      if (r >= (int)n) continue;
      float bx1 = sm.mtx.sx1[r], by1 = sm.mtx.sy1[r], bx2 = sm.mtx.sx2[r], by2 = sm.mtx.sy2[r];
      float bA = sm.mtx.sar[r];
      unsigned long long* rowp = mat + ((size_t)img * RANKS + r) * 16;
#pragma unroll
      for (int w2 = 0; w2 < 16; ++w2) {
        int c = w2 * 64 + lane;
        float lx = fmaxf(bx1, sm.mtx.sx1[c]), ly = fmaxf(by1, sm.mtx.sy1[c]);
        float rx = fminf(bx2, sm.mtx.sx2[c]), ry = fminf(by2, sm.mtx.sy2[c]);
        float iw = fmaxf(rx - lx, 0.f), ih = fmaxf(ry - ly, 0.f);
        float inter = iw * ih;
        float uu = bA + sm.mtx.sar[c] - inter;
        float ss = fmaf(2.0f, inter, -uu);
        float tt = uu * 0x1p-24f;
        bool sup = (uu > 0.f && ss > tt) || (c == r);
        unsigned long long b = __ballot(sup);
        if (lane == w2) rowp[w2] = b;
      }
    }
    __syncthreads();  // LDS reuse across vb
  }
}

__device__ void ph_scan2(SMem& sm, const unsigned long long* __restrict__ mat,
                         const Meta* __restrict__ meta, const float4* __restrict__ payr0,
                         const float4* __restrict__ payr1, float* __restrict__ out) {
  int tid = threadIdx.x, lane = tid & 63, wid = tid >> 6;
  for (int vb = blockIdx.x; vb < BB; vb += gridDim.x) {
    int img = vb;
    if (tid < MAXDET) sm.s2.wins[tid] = 0xFFFFFFFFu;
    unsigned n = meta[img].n_true;
    __syncthreads();
    if (wid == 0) {
      unsigned long long alive = 0ull;
      if (lane < 16) {
        int lo = lane * 64;
        alive = ((int)n >= lo + 64)
                    ? ~0ull
                    : (((int)n > lo) ? ((1ull << ((int)n - lo)) - 1ull) : 0ull);
      }
      const unsigned long long* mrow = mat + (size_t)img * RANKS * 16;
      for (int it = 0; it < MAXDET; ++it) {
        unsigned long long any = __ballot(alive != 0ull);
        if (any == 0ull) break;
        int f = __builtin_ctzll(any);
        unsigned long long w = __shfl(alive, f);
        int r = f * 64 + __builtin_ctzll(w);
        if (lane == 0) sm.s2.wins[it] = (unsigned)r;
        unsigned long long rowv = (lane < 16) ? mrow[r * 16 + lane] : 0ull;  // L2 read
        alive &= ~rowv;
      }
    }
    __syncthreads();
    if (tid < MAXDET) {
      unsigned r = sm.s2.wins[tid];
      float* row = sm.s2.lout + tid * 7;
      if (r == 0xFFFFFFFFu) {
        row[0] = 0.f; row[1] = 0.f; row[2] = 0.f; row[3] = 0.f;
        row[4] = 0.f; row[5] = 0.f; row[6] = 0.f;
      } else {
        float4 p0 = payr0[(size_t)img * RANKS + r];
        float4 p1 = payr1[(size_t)img * RANKS + r];
        row[0] = p0.x; row[1] = p0.y; row[2] = p0.z; row[3] = p0.w;
        row[4] = p1.x; row[5] = p1.y; row[6] = p1.z;
      }
    }
    __syncthreads();
    float4* go4 = reinterpret_cast<float4*>(out + (size_t)img * MAXDET * 7);
    const float4* lo4 = reinterpret_cast<const float4*>(sm.s2.lout);
    if (tid < MAXDET * 7 / 4) go4[tid] = lo4[tid];
    __syncthreads();
  }
}

__global__ void __launch_bounds__(256) k_mega(const float* __restrict__ regs,
                                              const float* __restrict__ clses,
                                              const float* __restrict__ anchors,
                                              float* __restrict__ out, char* __restrict__ ws) {
  __shared__ SMem sm;
  cg::grid_group grid = cg::this_grid();
  unsigned* histp = (unsigned*)(ws + HISTP_OFF);
  unsigned* hists = (unsigned*)(ws + HISTS_OFF);
  Meta* meta = (Meta*)(ws + META_OFF);
  unsigned* keys = (unsigned*)(ws + KEYS_OFF);
  float* ccs = (float*)(ws + CCS_OFF);
  int* preds = (int*)(ws + PREDS_OFF);
  unsigned* pkey = (unsigned*)(ws + PKEY_OFF);
  float* cand = (float*)(ws + CAND_OFF);
  float* boxr = (float*)(ws + BOXR_OFF);
  float4* payr0 = (float4*)(ws + PAYR_OFF);
  float4* payr1 = (float4*)(ws + PAYR_OFF + (size_t)BB * RANKS * 16);
  unsigned long long* mat = (unsigned long long*)(ws + MAT_OFF);
  int stride = gridDim.x * 256;
  int gt = blockIdx.x * 256 + threadIdx.x;

  // zero hists + meta
  for (int i = gt; i < (int)(ZERO_BYTES / 4); i += stride) ((unsigned*)ws)[i] = 0u;
  grid.sync();
  // pobj
  for (int g = gt; g < BB * NN; g += stride) {
    float pobj = regs[(size_t)g * 5 + 4];
    unsigned key = flipKey(pobj);
    pkey[g] = key;
    if (pobj >= 0.05f)
      atomicAdd(&histp[(size_t)(g / NN) * HBINS + ((key >> 16) - HBASE)], 1u);
  }
  grid.sync();
  ph_scan(sm, histp, meta, 0);
  grid.sync();
  ph_cand(regs, clses, pkey, meta, keys, ccs, preds, hists, 0);
  grid.sync();
  ph_scan(sm, hists, meta, 1);
  grid.sync();
  ph_cand(regs, clses, pkey, meta, keys, ccs, preds, hists, 1);
  grid.sync();
  ph_scan(sm, hists, meta, 2);
  grid.sync();
  ph_compact(regs, anchors, keys, ccs, preds, meta, cand);
  grid.sync();
  ph_rank(sm, cand, meta, boxr, payr0, payr1);
  grid.sync();
  ph_matrix(sm, boxr, meta, mat);
  grid.sync();
  ph_scan2(sm, mat, meta, payr0, payr1, out);
}

// ======================= FALLBACK (R21 pipeline, unchanged) =======================
__global__ void __launch_bounds__(256) k_zero(unsigned* __restrict__ p) {
  p[blockIdx.x * 256 + threadIdx.x] = 0u;
}

__global__ void __launch_bounds__(256) k_pobj(const float* __restrict__ regs,
                                              unsigned* __restrict__ pkey,
                                              unsigned* __restrict__ histp) {
  int g = blockIdx.x * 256 + threadIdx.x;
  float pobj = regs[(size_t)g * 5 + 4];
  unsigned key = flipKey(pobj);
  pkey[g] = key;
  if (pobj >= 0.05f)
    atomicAdd(&histp[(size_t)(g / NN) * HBINS + ((key >> 16) - HBASE)], 1u);
}

__global__ void __launch_bounds__(256) k_scan(const unsigned* __restrict__ hist,
                                              Meta* __restrict__ meta, int mode) {
  __shared__ unsigned part[256];
  __shared__ unsigned sfx[256];
  __shared__ int s_sel;
  __shared__ unsigned s_cum;
  int img = blockIdx.x;
  int t = threadIdx.x;
  const unsigned* h = hist + (size_t)img * HBINS;
  uint4 mine = reinterpret_cast<const uint4*>(h)[t];
  unsigned s = mine.x + mine.y + mine.z + mine.w;
  if (t == 0) { s_sel = -1; s_cum = 0; }
  part[t] = s;
  sfx[t] = s;
  __syncthreads();
  for (int d = 1; d < 256; d <<= 1) {
    unsigned v = (t + d < 256) ? sfx[t + d] : 0u;
    __syncthreads();
    sfx[t] += v;
    __syncthreads();
  }
  {
    unsigned incl = sfx[t];
    unsigned excl = incl - part[t];
    if (incl >= (unsigned)TOPK && excl < (unsigned)TOPK) { s_sel = t; s_cum = excl; }
  }
  __syncthreads();
  unsigned total = sfx[0];
  if (total < (unsigned)TOPK) {
    if (t == 0) {
      if (mode == 0) meta[img].b1p = HBASE + 1;
      else if (mode == 1) meta[img].b1c = HBASE + 1;
      else { meta[img].b1 = HBASE + 1; meta[img].n_true = total; }
    }
  } else if (t == s_sel) {
    unsigned cum = s_cum;
    unsigned vals[4] = {mine.x, mine.y, mine.z, mine.w};
    int sel = 0;
    unsigned c_ge = 0;
    for (int j = 3; j >= 0; --j) {
      if (cum + vals[j] >= (unsigned)TOPK) { sel = j; c_ge = cum + vals[j]; break; }
      cum += vals[j];
    }
    unsigned bin = HBASE + (unsigned)(4 * t + sel);
    if (mode == 0) meta[img].b1p = bin;
    else if (mode == 1) meta[img].b1c = bin;
    else {
      meta[img].b1 = bin;
      meta[img].n_true = (c_ge > (unsigned)TOPK) ? (unsigned)TOPK : c_ge;
    }
  }
}

__global__ void __launch_bounds__(256) k_cand(const float* __restrict__ regs,
                                              const float* __restrict__ clses,
                                              const unsigned* __restrict__ pkey,
                                              const Meta* __restrict__ meta,
                                              unsigned* __restrict__ keys,
                                              float* __restrict__ ccs,
                                              int* __restrict__ preds,
                                              unsigned* __restrict__ hists, int mode) {
  int g = blockIdx.x * 256 + threadIdx.x;
  int img = g / NN;
  unsigned pk = pkey[g];
  unsigned pk16 = pk >> 16;
  unsigned lo = (mode == 0) ? meta[img].b1p : meta[img].b1c;
  unsigned hi = (mode == 0) ? 0x10000u : meta[img].b1p;
  if (pk16 < lo || pk16 >= hi) {
    if (mode == 0) keys[g] = 0u;
    return;
  }
  const float4* r4 = reinterpret_cast<const float4*>(clses + (size_t)g * NCLS);
  float best = -1.0f;
  int bi = 0;
#pragma unroll
  for (int f = 0; f < 20; ++f) {
    float4 v = r4[f];
    int b0 = f * 4;
    if (v.x > best) { best = v.x; bi = b0 + 0; }
    if (v.y > best) { best = v.y; bi = b0 + 1; }
    if (v.z > best) { best = v.z; bi = b0 + 2; }
    if (v.w > best) { best = v.w; bi = b0 + 3; }
  }
  float pobj = unflipKey(pk);
  float sc = pobj * best;
  bool pass = (sc >= 0.05f);
  unsigned key = flipKey(pass ? sc : NEGV);
  keys[g] = key;
  ccs[g] = best;
  preds[g] = bi;
  if (pass) atomicAdd(&hists[(size_t)img * HBINS + ((key >> 16) - HBASE)], 1u);
}

__global__ void k_compact(const float* __restrict__ regs, const float* __restrict__ anchors,
                          const unsigned* __restrict__ keys, const float* __restrict__ ccs,
                          const int* __restrict__ preds, Meta* __restrict__ meta,
                          float* __restrict__ cand) {
  int img = blockIdx.x / BPI_C;
  int i = (blockIdx.x % BPI_C) * 256 + threadIdx.x;
  if (i >= NN) return;
  int lane = threadIdx.x & 63;
  unsigned long long lt = (1ull << lane) - 1ull;
  size_t g = (size_t)img * NN + (size_t)i;
  unsigned key = keys[g];
  bool take = (key >> 16) >= meta[img].b1;
  unsigned long long mA = __ballot(take);
  if (!take) return;
  int leader = __builtin_ctzll(mA);
  unsigned base = 0;
  if (lane == leader) base = atomicAdd(&meta[img].cnt, (unsigned)__popcll(mA));
  base = __shfl(base, leader);
  unsigned pos = base + (unsigned)__popcll(mA & lt);
  if (pos >= CAND_CAP) return;
  decode_store(regs, anchors, img, i, ccs[g], (float)preds[g], unflipKey(key), pos, cand);
}

__global__ void __launch_bounds__(256) k_rank(const float* __restrict__ cand,
                                              const Meta* __restrict__ meta,
                                              float* __restrict__ boxr,
                                              float4* __restrict__ payr0,
                                              float4* __restrict__ payr1) {
  const size_t S2 = (size_t)BB * CAND_CAP;
  const int NR = BB * RANKS;
  __shared__ unsigned long long kk[CAND_CAP];
  int img = blockIdx.x >> 5;
  int part = blockIdx.x & 31;
  int tid = threadIdx.x;
  unsigned nload = meta[img].cnt;
  if (nload > CAND_CAP) nload = CAND_CAP;
  for (int i = tid; i < CAND_CAP; i += 256) {
    unsigned long long kv = 0ull;
    if (i < (int)nload) {
      float sc = cand[7 * S2 + (size_t)img * CAND_CAP + i];
      unsigned ai = reinterpret_cast<const unsigned*>(cand + 8 * S2)[(size_t)img * CAND_CAP + i];
      kv = ((unsigned long long)flipKey(sc) << 16) |
           (unsigned long long)((0x7FFFu - ai) & 0xFFFFu);
    }
    kk[i] = kv;
  }
  __syncthreads();
  int slot = part * 64 + (tid >> 2);
  int qtr = tid & 3;
  unsigned long long myk = kk[slot];
  unsigned rank = 0;
  for (int q = qtr * 512; q < qtr * 512 + 512; ++q) rank += (kk[q] > myk) ? 1u : 0u;
  rank += (unsigned)__builtin_amdgcn_update_dpp(0, (int)rank, 0xB1, 0xF, 0xF, true);
  rank += (unsigned)__builtin_amdgcn_update_dpp(0, (int)rank, 0x4E, 0xF, 0xF, true);
  if (qtr == 0 && slot < (int)nload && rank < RANKS) {
    size_t o = (size_t)img * CAND_CAP + slot;
    float x1 = cand[0 * S2 + o], y1 = cand[1 * S2 + o];
    float x2 = cand[2 * S2 + o], y2 = cand[3 * S2 + o];
    float obj = cand[4 * S2 + o], cc = cand[5 * S2 + o];
    float cp = cand[6 * S2 + o], sc = cand[7 * S2 + o];
    float offv = cp * 4096.0f;
    float a1 = x1 + offv, b1v = y1 + offv, a2 = x2 + offv, b2v = y2 + offv;
    size_t ro = (size_t)img * RANKS + rank;
    boxr[0 * NR + ro] = a1;
    boxr[1 * NR + ro] = b1v;
    boxr[2 * NR + ro] = a2;
    boxr[3 * NR + ro] = b2v;
    boxr[4 * NR + ro] = (a2 - a1) * (b2v - b1v);
    payr0[ro] = make_float4(x1, y1, x2, y2);
    payr1[ro] = make_float4(obj, cc, cp, sc);
  }
}

__global__ void __launch_bounds__(256) k_matrix(const float* __restrict__ boxr,
                                                const Meta* __restrict__ meta,
                                                unsigned long long* __restrict__ mat) {
  const int NR = BB * RANKS;
  __shared__ float sx1[RANKS], sy1[RANKS], sx2[RANKS], sy2[RANKS], sar[RANKS];
  int img = blockIdx.x >> 6;
  int part = blockIdx.x & 63;
  int tid = threadIdx.x, lane = tid & 63, wid = tid >> 6;
  for (int i = tid; i < RANKS; i += 256) {
    int g = img * RANKS + i;
    sx1[i] = boxr[0 * NR + g];
    sy1[i] = boxr[1 * NR + g];
    sx2[i] = boxr[2 * NR + g];
    sy2[i] = boxr[3 * NR + g];
    sar[i] = boxr[4 * NR + g];
  }
  unsigned n = meta[img].n_true;
  __syncthreads();
#pragma unroll
  for (int rr = 0; rr < 4; ++rr) {
    int r = part * 16 + wid * 4 + rr;
    if (r >= (int)n) continue;
    float bx1 = sx1[r], by1 = sy1[r], bx2 = sx2[r], by2 = sy2[r], bA = sar[r];
    unsigned long long* rowp = mat + ((size_t)img * RANKS + r) * 16;
#pragma unroll
    for (int w2 = 0; w2 < 16; ++w2) {
      int c = w2 * 64 + lane;
      float lx = fmaxf(bx1, sx1[c]), ly = fmaxf(by1, sy1[c]);
      float rx = fminf(bx2, sx2[c]), ry = fminf(by2, sy2[c]);
      float iw = fmaxf(rx - lx, 0.f), ih = fmaxf(ry - ly, 0.f);
      float inter = iw * ih;
      float uu = bA + sar[c] - inter;
      float ss = fmaf(2.0f, inter, -uu);
      float tt = uu * 0x1p-24f;
      bool sup = (uu > 0.f && ss > tt) || (c == r);
      unsigned long long b = __ballot(sup);
      if (lane == w2) rowp[w2] = b;
    }
  }
}

__global__ void __launch_bounds__(1024, 1) k_scan2(const unsigned long long* __restrict__ mat,
                                                   const Meta* __restrict__ meta,
                                                   const float4* __restrict__ payr0,
                                                   const float4* __restrict__ payr1,
                                                   float* __restrict__ out) {
  __shared__ unsigned long long smat[RANKS * 16];
  __shared__ unsigned wins[MAXDET];
  __shared__ float4 lout4[MAXDET * 7 / 4];
  int img = blockIdx.x, tid = threadIdx.x, lane = tid & 63, wid = tid >> 6;
  const uint4* gm = reinterpret_cast<const uint4*>(mat + (size_t)img * RANKS * 16);
  uint4* sm4 = reinterpret_cast<uint4*>(smat);
  for (int i = tid; i < RANKS * 16 / 2; i += 1024) sm4[i] = gm[i];
  if (tid < MAXDET) wins[tid] = 0xFFFFFFFFu;
  unsigned n = meta[img].n_true;
  __syncthreads();
  if (wid == 0) {
    unsigned long long alive = 0ull;
    if (lane < 16) {
      int lo = lane * 64;
      alive = ((int)n >= lo + 64) ? ~0ull
                                  : (((int)n > lo) ? ((1ull << ((int)n - lo)) - 1ull) : 0ull);
    }
    for (int it = 0; it < MAXDET; ++it) {
      unsigned long long any = __ballot(alive != 0ull);
      if (any == 0ull) break;
      int f = __builtin_ctzll(any);
      unsigned long long w = __shfl(alive, f);
      int r = f * 64 + __builtin_ctzll(w);
      if (lane == 0) wins[it] = (unsigned)r;
      unsigned long long rowv = (lane < 16) ? smat[r * 16 + lane] : 0ull;
      alive &= ~rowv;
    }
  }
  __syncthreads();
  if (tid < MAXDET) {
    unsigned r = wins[tid];
    float* row = reinterpret_cast<float*>(lout4) + tid * 7;
    if (r == 0xFFFFFFFFu) {
      row[0] = 0.f; row[1] = 0.f; row[2] = 0.f; row[3] = 0.f;
      row[4] = 0.f; row[5] = 0.f; row[6] = 0.f;
    } else {
      float4 p0 = payr0[(size_t)img * RANKS + r];
      float4 p1 = payr1[(size_t)img * RANKS + r];
      row[0] = p0.x; row[1] = p0.y; row[2] = p0.z; row[3] = p0.w;
      row[4] = p1.x; row[5] = p1.y; row[6] = p1.z;
    }
  }
  __syncthreads();
  float4* go4 = reinterpret_cast<float4*>(out + (size_t)img * MAXDET * 7);
  if (tid < MAXDET * 7 / 4) go4[tid] = lout4[tid];
}

// ---------------- launch ----------------
extern "C" void kernel_launch(void* const* d_in, const int* in_sizes, int n_in,
                              void* d_out, int out_size, void* d_ws, size_t ws_size,
                              hipStream_t stream) {
  const float* regs = (const float*)d_in[0];
  const float* clses = (const float*)d_in[1];
  const float* anchors = (const float*)d_in[2];
  float* out = (float*)d_out;
  char* ws = (char*)d_ws;

  unsigned* histp = (unsigned*)(ws + HISTP_OFF);
  unsigned* hists = (unsigned*)(ws + HISTS_OFF);
  Meta* meta = (Meta*)(ws + META_OFF);
  unsigned* keys = (unsigned*)(ws + KEYS_OFF);
  float* ccs = (float*)(ws + CCS_OFF);
  int* preds = (int*)(ws + PREDS_OFF);
  unsigned* pkey = (unsigned*)(ws + PKEY_OFF);
  float* cand = (float*)(ws + CAND_OFF);
  float* boxr = (float*)(ws + BOXR_OFF);
  float4* payr0 = (float4*)(ws + PAYR_OFF);
  float4* payr1 = (float4*)(ws + PAYR_OFF + (size_t)BB * RANKS * 16);
  unsigned long long* mat = (unsigned long long*)(ws + MAT_OFF);

  // cooperative mega-kernel: grid sized to guaranteed co-residency
  int nb = 0;
  hipError_t oe = hipOccupancyMaxActiveBlocksPerMultiprocessor(&nb, k_mega, 256, 0);
  int grid = 1024;
  if (oe == hipSuccess && nb >= 1) {
    long cap = (long)nb * 256;  // 256 CUs
    grid = (int)((cap < 1024) ? cap : 1024);
  } else {
    grid = 256;
  }
  void* args[] = {(void*)&regs, (void*)&clses, (void*)&anchors, (void*)&out, (void*)&ws};
  hipError_t le = hipLaunchCooperativeKernel((const void*)k_mega, dim3(grid), dim3(256),
                                             args, 0, stream);
  if (le == hipSuccess) return;

  // fallback: R21 pipeline (deterministic, same output)
  k_zero<<<(int)(ZERO_BYTES / 1024), 256, 0, stream>>>((unsigned*)ws);
  int rblocks = BB * NN / 256;
  k_pobj<<<rblocks, 256, 0, stream>>>(regs, pkey, histp);
  k_scan<<<BB, 256, 0, stream>>>(histp, meta, 0);
  k_cand<<<rblocks, 256, 0, stream>>>(regs, clses, pkey, meta, keys, ccs, preds, hists, 0);
  k_scan<<<BB, 256, 0, stream>>>(hists, meta, 1);
  k_cand<<<rblocks, 256, 0, stream>>>(regs, clses, pkey, meta, keys, ccs, preds, hists, 1);
  k_scan<<<BB, 256, 0, stream>>>(hists, meta, 2);
  k_compact<<<BB * BPI_C, 256, 0, stream>>>(regs, anchors, keys, ccs, preds, meta, cand);
  k_rank<<<BB * 32, 256, 0, stream>>>(cand, meta, boxr, payr0, payr1);
  k_matrix<<<BB * 64, 256, 0, stream>>>(boxr, meta, mat);
  k_scan2<<<BB, 1024, 0, stream>>>(mat, meta, payr0, payr1, out);
}

// Round 23
// 147.070 us; speedup vs baseline: 6.6653x; 6.6653x over previous
//
#include <hip/hip_runtime.h>
#include <math.h>

#define BB 16
#define NN 25200
#define NCLS 80
#define TOPK 1000
#define MAXDET 100
#define CAND_CAP 2048
#define RANKS 1024
#define HBINS 1024
#define HBASE 0xBD00u
#define BPI 99  // blocks per image: ceil(25200/256)
static constexpr float NEGV = -1000000000.0f;
static constexpr float IMGSZ = 640.0f;

// b1p: 1000th-largest pobj bin; b1c: 1000th-largest score bin among pass-1 candidates;
// b1/n_true: final cutoff; cnt: compact counter.
struct Meta {
  unsigned b1p;
  unsigned b1c;
  unsigned b1;
  unsigned n_true;
  unsigned cnt;
  unsigned pad0, pad1, pad2;
};

__device__ __forceinline__ unsigned flipKey(float f) {
  unsigned u = __float_as_uint(f);
  return (u & 0x80000000u) ? ~u : (u | 0x80000000u);
}
__device__ __forceinline__ float unflipKey(unsigned k) {
  unsigned u = (k & 0x80000000u) ? (k & 0x7FFFFFFFu) : ~k;
  return __uint_as_float(u);
}

// ---- block-local cutoff scan over a 1024-bin suffix histogram (replaces k_scan) ----
// Every consumer block recomputes the cutoff from the (launch-boundary-complete)
// histogram: read 1024 bins + 8-step Hillis-Steele suffix scan in LDS (~2 KB).
// Returns via LDS: s_bin = cutoff bin (absolute k16), s_cge = #keys >= cutoff,
// s_tot = total. Caller applies the total<TOPK fallback.
struct ScanLds {
  unsigned part[256];
  unsigned sfx[256];
  int sel;
  unsigned bin, cge, tot;
};
__device__ void block_cutoff(ScanLds& L, const unsigned* __restrict__ h) {
  int t = threadIdx.x;
  uint4 mine = reinterpret_cast<const uint4*>(h)[t];  // bins 4t..4t+3
  unsigned s = mine.x + mine.y + mine.z + mine.w;
  if (t == 0) L.sel = -1;
  L.part[t] = s;
  L.sfx[t] = s;
  __syncthreads();
  for (int d = 1; d < 256; d <<= 1) {
    unsigned v = (t + d < 256) ? L.sfx[t + d] : 0u;
    __syncthreads();
    L.sfx[t] += v;
    __syncthreads();
  }
  {
    unsigned incl = L.sfx[t];
    unsigned excl = incl - L.part[t];
    if (incl >= (unsigned)TOPK && excl < (unsigned)TOPK) L.sel = t;
  }
  if (t == 0) L.tot = L.sfx[0];
  __syncthreads();
  if (t == L.sel) {
    unsigned excl = L.sfx[t] - L.part[t];
    unsigned cum = excl;
    unsigned vals[4] = {mine.x, mine.y, mine.z, mine.w};
    int sel4 = 0;
    unsigned c_ge = 0;
    for (int j = 3; j >= 0; --j) {  // high bin -> low bin
      if (cum + vals[j] >= (unsigned)TOPK) { sel4 = j; c_ge = cum + vals[j]; break; }
      cum += vals[j];
    }
    L.bin = HBASE + (unsigned)(4 * t + sel4);
    L.cge = c_ge;
  }
  __syncthreads();
}

// ---------------- zero histp + hists + meta (129 KB) ----------------
__global__ void __launch_bounds__(256) k_zero(unsigned* __restrict__ p) {
  p[blockIdx.x * 256 + threadIdx.x] = 0u;  // grid sized exactly to region
}

// ---------------- phase A: pobj keys + pobj histogram (8 MB read instead of 129) -------
// score = pobj*classmax <= pobj (class scores in [0,1)): pobj bounds the score from above.
__global__ void __launch_bounds__(256) k_pobj(const float* __restrict__ regs,
                                              unsigned* __restrict__ pkey,
                                              unsigned* __restrict__ histp) {
  int g = blockIdx.x * 256 + threadIdx.x;  // grid = BB*NN/256 = 1575 exactly
  float pobj = regs[(size_t)g * 5 + 4];
  unsigned key = flipKey(pobj);
  pkey[g] = key;
  if (pobj >= 0.05f)
    atomicAdd(&histp[(size_t)(g / NN) * HBINS + ((key >> 16) - HBASE)], 1u);
}

// ---------------- phase B: score rows in a pobj-bin range (cutoff inlined) -------------
// mode 0: lo = b1p (computed from histp in prologue; published to meta.b1p)
// mode 1: lo = b1c (computed from hists in prologue),  hi = meta.b1p (from mode 0)
// Union = {pk16 >= b1c} provably contains every possible top-TOPK row.
__global__ void __launch_bounds__(256) k_cand(const float* __restrict__ regs,
                                              const float* __restrict__ clses,
                                              const unsigned* __restrict__ pkey,
                                              const unsigned* __restrict__ cuthist,
                                              Meta* __restrict__ meta,
                                              unsigned* __restrict__ keys,
                                              float* __restrict__ ccs,
                                              int* __restrict__ preds,
                                              unsigned* __restrict__ hists, int mode) {
  __shared__ ScanLds L;
  int img = blockIdx.x / BPI;
  int i = (blockIdx.x % BPI) * 256 + threadIdx.x;
  block_cutoff(L, cuthist + (size_t)img * HBINS);
  unsigned cut = (L.tot < (unsigned)TOPK) ? (HBASE + 1) : L.bin;
  unsigned lo, hi;
  if (mode == 0) {
    lo = cut;
    hi = 0x10000u;
    if (threadIdx.x == 0 && (blockIdx.x % BPI) == 0) meta[img].b1p = cut;
  } else {
    lo = cut;
    hi = meta[img].b1p;  // published by mode-0 kernel (previous launch)
    if (threadIdx.x == 0 && (blockIdx.x % BPI) == 0) meta[img].b1c = cut;
  }
  if (i >= NN) return;
  size_t g = (size_t)img * NN + (size_t)i;
  unsigned pk = pkey[g];
  unsigned pk16 = pk >> 16;
  if (pk16 < lo || pk16 >= hi) {
    if (mode == 0) keys[g] = 0u;  // full coverage: unscored rows never pass compact
    return;
  }
  const float4* r4 = reinterpret_cast<const float4*>(clses + g * NCLS);
  float best = -1.0f;
  int bi = 0;
#pragma unroll
  for (int f = 0; f < 20; ++f) {
    float4 v = r4[f];
    int b0 = f * 4;
    if (v.x > best) { best = v.x; bi = b0 + 0; }
    if (v.y > best) { best = v.y; bi = b0 + 1; }
    if (v.z > best) { best = v.z; bi = b0 + 2; }
    if (v.w > best) { best = v.w; bi = b0 + 3; }
  }
  float pobj = unflipKey(pk);
  float sc = pobj * best;
  bool pass = (sc >= 0.05f);
  unsigned key = flipKey(pass ? sc : NEGV);
  keys[g] = key;
  ccs[g] = best;
  preds[g] = bi;
  if (pass) atomicAdd(&hists[(size_t)img * HBINS + ((key >> 16) - HBASE)], 1u);
}

// ---------------- compaction (final cutoff inlined; publishes b1/n_true) ----------------
__global__ void __launch_bounds__(256) k_compact(const float* __restrict__ regs,
                                                 const float* __restrict__ anchors,
                                                 const unsigned* __restrict__ keys,
                                                 const float* __restrict__ ccs,
                                                 const int* __restrict__ preds,
                                                 const unsigned* __restrict__ hists,
                                                 Meta* __restrict__ meta,
                                                 float* __restrict__ cand) {
  __shared__ ScanLds L;
  const size_t S2 = (size_t)BB * CAND_CAP;
  int img = blockIdx.x / BPI;
  int i = (blockIdx.x % BPI) * 256 + threadIdx.x;
  block_cutoff(L, hists + (size_t)img * HBINS);
  unsigned b1;
  unsigned n_true;
  if (L.tot < (unsigned)TOPK) {
    b1 = HBASE + 1;
    n_true = L.tot;
  } else {
    b1 = L.bin;
    n_true = (L.cge > (unsigned)TOPK) ? (unsigned)TOPK : L.cge;
  }
  if (threadIdx.x == 0 && (blockIdx.x % BPI) == 0) {
    meta[img].b1 = b1;
    meta[img].n_true = n_true;  // consumed by k_rank/k_matrix/k_scan2 (later launches)
  }
  if (i >= NN) return;
  int lane = threadIdx.x & 63;
  unsigned long long lt = (1ull << lane) - 1ull;
  size_t g = (size_t)img * NN + (size_t)i;
  unsigned key = keys[g];
  bool take = (key >> 16) >= b1;
  unsigned long long mA = __ballot(take);
  if (!take) return;
  int leader = __builtin_ctzll(mA);
  unsigned base = 0;
  if (lane == leader) base = atomicAdd(&meta[img].cnt, (unsigned)__popcll(mA));
  base = __shfl(base, leader);
  unsigned pos = base + (unsigned)__popcll(mA & lt);
  if (pos >= CAND_CAP) return;
  const float* r = regs + g * 5;
  float d0 = r[0], d1 = r[1], d2 = r[2], d3 = r[3], obj = r[4];
  const float* a = anchors + (size_t)i * 4;
  float ax1 = a[0], ay1 = a[1], ax2 = a[2], ay2 = a[3];
  float aw = ax2 - ax1, ah = ay2 - ay1;
  float acx = (ax1 + ax2) * 0.5f, acy = (ay1 + ay2) * 0.5f;
  float cx = acx + d0 * aw, cy = acy + d1 * ah;
  float w = aw * expf(d2), h = ah * expf(d3);
  float hw = 0.5f * w, hh = 0.5f * h;
  float x1 = fminf(fmaxf(cx - hw, 0.0f), IMGSZ);
  float y1 = fminf(fmaxf(cy - hh, 0.0f), IMGSZ);
  float x2 = fminf(fmaxf(cx + hw, 0.0f), IMGSZ);
  float y2 = fminf(fmaxf(cy + hh, 0.0f), IMGSZ);
  size_t o = (size_t)img * CAND_CAP + pos;
  cand[0 * S2 + o] = x1;
  cand[1 * S2 + o] = y1;
  cand[2 * S2 + o] = x2;
  cand[3 * S2 + o] = y2;
  cand[4 * S2 + o] = obj;
  cand[5 * S2 + o] = ccs[g];
  cand[6 * S2 + o] = (float)preds[g];
  cand[7 * S2 + o] = unflipKey(key);
  reinterpret_cast<unsigned*>(cand + 8 * S2)[o] = (unsigned)i;
}

// ---------------- rank by counting: rank = #bigger 48-bit keys; scatter to rank space ----
__global__ void __launch_bounds__(256) k_rank(const float* __restrict__ cand,
                                              const Meta* __restrict__ meta,
                                              float* __restrict__ boxr,
                                              float4* __restrict__ payr0,
                                              float4* __restrict__ payr1) {
  const size_t S2 = (size_t)BB * CAND_CAP;
  const int NR = BB * RANKS;
  __shared__ unsigned long long kk[CAND_CAP];  // 16 KB
  int img = blockIdx.x >> 5;
  int part = blockIdx.x & 31;
  int tid = threadIdx.x;
  unsigned nload = meta[img].cnt;
  if (nload > CAND_CAP) nload = CAND_CAP;
  for (int i = tid; i < CAND_CAP; i += 256) {
    unsigned long long kv = 0ull;
    if (i < (int)nload) {
      float sc = cand[7 * S2 + (size_t)img * CAND_CAP + i];
      unsigned ai = reinterpret_cast<const unsigned*>(cand + 8 * S2)[(size_t)img * CAND_CAP + i];
      kv = ((unsigned long long)flipKey(sc) << 16) |
           (unsigned long long)((0x7FFFu - ai) & 0xFFFFu);  // unique via ai
    }
    kk[i] = kv;
  }
  __syncthreads();
  int slot = part * 64 + (tid >> 2);
  int qtr = tid & 3;
  unsigned long long myk = kk[slot];
  unsigned rank = 0;
  for (int q = qtr * 512; q < qtr * 512 + 512; ++q) rank += (kk[q] > myk) ? 1u : 0u;
  rank += (unsigned)__builtin_amdgcn_update_dpp(0, (int)rank, 0xB1, 0xF, 0xF, true);
  rank += (unsigned)__builtin_amdgcn_update_dpp(0, (int)rank, 0x4E, 0xF, 0xF, true);
  if (qtr == 0 && slot < (int)nload && rank < RANKS) {
    size_t o = (size_t)img * CAND_CAP + slot;
    float x1 = cand[0 * S2 + o], y1 = cand[1 * S2 + o];
    float x2 = cand[2 * S2 + o], y2 = cand[3 * S2 + o];
    float obj = cand[4 * S2 + o], cc = cand[5 * S2 + o];
    float cp = cand[6 * S2 + o], sc = cand[7 * S2 + o];
    float offv = cp * 4096.0f;
    float a1 = x1 + offv, b1v = y1 + offv, a2 = x2 + offv, b2v = y2 + offv;
    size_t ro = (size_t)img * RANKS + rank;
    boxr[0 * NR + ro] = a1;
    boxr[1 * NR + ro] = b1v;
    boxr[2 * NR + ro] = a2;
    boxr[3 * NR + ro] = b2v;
    boxr[4 * NR + ro] = (a2 - a1) * (b2v - b1v);
    payr0[ro] = make_float4(x1, y1, x2, y2);
    payr1[ro] = make_float4(obj, cc, cp, sc);
  }
}

// ---------------- suppression bit-matrix in rank space (parallel) ----------------
__global__ void __launch_bounds__(256) k_matrix(const float* __restrict__ boxr,
                                                const Meta* __restrict__ meta,
                                                unsigned long long* __restrict__ mat) {
  const int NR = BB * RANKS;
  __shared__ float sx1[RANKS], sy1[RANKS], sx2[RANKS], sy2[RANKS], sar[RANKS];  // 20 KB
  int img = blockIdx.x >> 6;
  int part = blockIdx.x & 63;
  int tid = threadIdx.x, lane = tid & 63, wid = tid >> 6;
  for (int i = tid; i < RANKS; i += 256) {
    int g = img * RANKS + i;
    sx1[i] = boxr[0 * NR + g];
    sy1[i] = boxr[1 * NR + g];
    sx2[i] = boxr[2 * NR + g];
    sy2[i] = boxr[3 * NR + g];
    sar[i] = boxr[4 * NR + g];
  }
  unsigned n = meta[img].n_true;
  __syncthreads();
#pragma unroll
  for (int rr = 0; rr < 4; ++rr) {
    int r = part * 16 + wid * 4 + rr;
    if (r >= (int)n) continue;  // wave-uniform
    float bx1 = sx1[r], by1 = sy1[r], bx2 = sx2[r], by2 = sy2[r], bA = sar[r];
    unsigned long long* rowp = mat + ((size_t)img * RANKS + r) * 16;
#pragma unroll
    for (int w2 = 0; w2 < 16; ++w2) {
      int c = w2 * 64 + lane;
      float lx = fmaxf(bx1, sx1[c]), ly = fmaxf(by1, sy1[c]);
      float rx = fminf(bx2, sx2[c]), ry = fminf(by2, sy2[c]);
      float iw = fmaxf(rx - lx, 0.f), ih = fmaxf(ry - ly, 0.f);
      float inter = iw * ih;
      float uu = bA + sar[c] - inter;
      float ss = fmaf(2.0f, inter, -uu);  // exact 2i-u (Sterbenz in decision region)
      float tt = uu * 0x1p-24f;           // RN(i/u)>0.5 <=> ss>tt
      bool sup = (uu > 0.f && ss > tt) || (c == r);
      unsigned long long b = __ballot(sup);
      if (lane == w2) rowp[w2] = b;
    }
  }
}

// ---------------- serial scan: 1024-thread staging, trivial chain ----------------
__global__ void __launch_bounds__(1024, 1) k_scan2(const unsigned long long* __restrict__ mat,
                                                   const Meta* __restrict__ meta,
                                                   const float4* __restrict__ payr0,
                                                   const float4* __restrict__ payr1,
                                                   float* __restrict__ out) {
  __shared__ unsigned long long smat[RANKS * 16];  // 128 KB
  __shared__ unsigned wins[MAXDET];
  __shared__ float4 lout4[MAXDET * 7 / 4];
  int img = blockIdx.x, tid = threadIdx.x, lane = tid & 63, wid = tid >> 6;
  const uint4* gm = reinterpret_cast<const uint4*>(mat + (size_t)img * RANKS * 16);
  uint4* sm4 = reinterpret_cast<uint4*>(smat);
  for (int i = tid; i < RANKS * 16 / 2; i += 1024) sm4[i] = gm[i];
  if (tid < MAXDET) wins[tid] = 0xFFFFFFFFu;
  unsigned n = meta[img].n_true;
  __syncthreads();
  if (wid == 0) {
    unsigned long long alive = 0ull;
    if (lane < 16) {
      int lo = lane * 64;
      alive = ((int)n >= lo + 64) ? ~0ull
                                  : (((int)n > lo) ? ((1ull << ((int)n - lo)) - 1ull) : 0ull);
    }
    for (int it = 0; it < MAXDET; ++it) {
      unsigned long long any = __ballot(alive != 0ull);
      if (any == 0ull) break;  // rest of rows zero via sentinel
      int f = __builtin_ctzll(any);
      unsigned long long w = __shfl(alive, f);
      int r = f * 64 + __builtin_ctzll(w);
      if (lane == 0) wins[it] = (unsigned)r;
      unsigned long long rowv = (lane < 16) ? smat[r * 16 + lane] : 0ull;
      alive &= ~rowv;  // diag bit clears the winner itself
    }
  }
  __syncthreads();
  if (tid < MAXDET) {
    unsigned r = wins[tid];
    float* row = reinterpret_cast<float*>(lout4) + tid * 7;
    if (r == 0xFFFFFFFFu) {
      row[0] = 0.f; row[1] = 0.f; row[2] = 0.f; row[3] = 0.f;
      row[4] = 0.f; row[5] = 0.f; row[6] = 0.f;
    } else {
      float4 p0 = payr0[(size_t)img * RANKS + r];
      float4 p1 = payr1[(size_t)img * RANKS + r];
      row[0] = p0.x; row[1] = p0.y; row[2] = p0.z; row[3] = p0.w;
      row[4] = p1.x; row[5] = p1.y; row[6] = p1.z;
    }
  }
  __syncthreads();
  float4* go4 = reinterpret_cast<float4*>(out + (size_t)img * MAXDET * 7);
  if (tid < MAXDET * 7 / 4) go4[tid] = lout4[tid];
}

// ---------------- launch (8 dispatches) ----------------
extern "C" void kernel_launch(void* const* d_in, const int* in_sizes, int n_in,
                              void* d_out, int out_size, void* d_ws, size_t ws_size,
                              hipStream_t stream) {
  const float* regs = (const float*)d_in[0];
  const float* clses = (const float*)d_in[1];
  const float* anchors = (const float*)d_in[2];
  float* out = (float*)d_out;
  char* ws = (char*)d_ws;

  constexpr size_t HISTP_OFF = 0;                      // 64 KB pobj hist
  constexpr size_t HISTS_OFF = 65536;                  // 64 KB score hist
  constexpr size_t META_OFF = 131072;                  // 1 KB
  constexpr size_t ZERO_BYTES = 132096;                // 129*1024: hists+meta only
  constexpr size_t KEYS_OFF = 132096;                  // fully written by k_cand mode 0
  constexpr size_t ARR_BYTES = (size_t)BB * NN * 4;    // 1,612,800
  constexpr size_t CCS_OFF = KEYS_OFF + ARR_BYTES;
  constexpr size_t PREDS_OFF = CCS_OFF + ARR_BYTES;
  constexpr size_t PKEY_OFF = PREDS_OFF + ARR_BYTES;
  constexpr size_t CAND_OFF = PKEY_OFF + ARR_BYTES;
  constexpr size_t CAND_BYTES = (size_t)9 * BB * CAND_CAP * 4;  // 1.18 MB
  constexpr size_t BOXR_OFF = CAND_OFF + CAND_BYTES;
  constexpr size_t BOXR_BYTES = (size_t)5 * BB * RANKS * 4;  // 320 KB
  constexpr size_t PAYR_OFF = BOXR_OFF + BOXR_BYTES;
  constexpr size_t PAYR_BYTES = (size_t)2 * BB * RANKS * 16;  // 512 KB
  constexpr size_t MAT_OFF = PAYR_OFF + PAYR_BYTES;
  // MAT: BB * RANKS * 16 u64 = 2 MB

  unsigned* histp = (unsigned*)(ws + HISTP_OFF);
  unsigned* hists = (unsigned*)(ws + HISTS_OFF);
  Meta* meta = (Meta*)(ws + META_OFF);
  unsigned* keys = (unsigned*)(ws + KEYS_OFF);
  float* ccs = (float*)(ws + CCS_OFF);
  int* preds = (int*)(ws + PREDS_OFF);
  unsigned* pkey = (unsigned*)(ws + PKEY_OFF);
  float* cand = (float*)(ws + CAND_OFF);
  float* boxr = (float*)(ws + BOXR_OFF);
  float4* payr0 = (float4*)(ws + PAYR_OFF);
  float4* payr1 = (float4*)(ws + PAYR_OFF + (size_t)BB * RANKS * 16);
  unsigned long long* mat = (unsigned long long*)(ws + MAT_OFF);

  // zero hists + meta every launch (keys covered by k_cand mode 0's full write)
  k_zero<<<(int)(ZERO_BYTES / 1024), 256, 0, stream>>>((unsigned*)ws);

  k_pobj<<<BB * NN / 256, 256, 0, stream>>>(regs, pkey, histp);
  k_cand<<<BB * BPI, 256, 0, stream>>>(regs, clses, pkey, histp, meta, keys, ccs, preds,
                                       hists, 0);
  k_cand<<<BB * BPI, 256, 0, stream>>>(regs, clses, pkey, hists, meta, keys, ccs, preds,
                                       hists, 1);
  k_compact<<<BB * BPI, 256, 0, stream>>>(regs, anchors, keys, ccs, preds, hists, meta, cand);
  k_rank<<<BB * 32, 256, 0, stream>>>(cand, meta, boxr, payr0, payr1);
  k_matrix<<<BB * 64, 256, 0, stream>>>(boxr, meta, mat);
  k_scan2<<<BB, 1024, 0, stream>>>(mat, meta, payr0, payr1, out);
}

// Round 24
// 146.565 us; speedup vs baseline: 6.6882x; 1.0034x over previous
//
#include <hip/hip_runtime.h>
#include <math.h>

#define BB 16
#define NN 25200
#define NCLS 80
#define TOPK 1000
#define MAXDET 100
#define CAND_CAP 2048
#define RANKS 1024
#define HBINS 1024
#define HBASE 0xBD00u
#define BPI 99  // blocks per image: ceil(25200/256)
static constexpr float NEGV = -1000000000.0f;
static constexpr float IMGSZ = 640.0f;

struct Meta {
  unsigned b1p;
  unsigned b1c;
  unsigned b1;
  unsigned n_true;
  unsigned cnt;
  unsigned pad0, pad1, pad2;
};

__device__ __forceinline__ unsigned flipKey(float f) {
  unsigned u = __float_as_uint(f);
  return (u & 0x80000000u) ? ~u : (u | 0x80000000u);
}
__device__ __forceinline__ float unflipKey(unsigned k) {
  unsigned u = (k & 0x80000000u) ? (k & 0x7FFFFFFFu) : ~k;
  return __uint_as_float(u);
}

// ---- BARRIER-FREE block cutoff: wave 0 only, DPP/shfl suffix scan ----
// R23's 256-thread version used 17 __syncthreads per block x 1584 blocks x 3 kernels.
// Here: lane l owns bins [16l,16l+16); 6-step __shfl_down suffix scan across 64 lanes;
// selected lane walks its 16 bins; publishes {bin,cge,tot} to LDS. ONE barrier (caller).
struct CutRes {
  unsigned bin, cge, tot;
};
__device__ __forceinline__ void wave_cutoff(CutRes& R, const unsigned* __restrict__ h) {
  if (threadIdx.x < 64) {
    int lane = threadIdx.x;
    const uint4* h4 = reinterpret_cast<const uint4*>(h) + lane * 4;
    uint4 q0 = h4[0], q1 = h4[1], q2 = h4[2], q3 = h4[3];
    unsigned v[16] = {q0.x, q0.y, q0.z, q0.w, q1.x, q1.y, q1.z, q1.w,
                      q2.x, q2.y, q2.z, q2.w, q3.x, q3.y, q3.z, q3.w};
    unsigned s = 0;
#pragma unroll
    for (int j = 0; j < 16; ++j) s += v[j];
    unsigned run = s;
#pragma unroll
    for (int d = 1; d < 64; d <<= 1) {
      unsigned o = __shfl_down(run, d);
      if (lane + d < 64) run += o;
    }
    unsigned incl = run;          // sum over lanes [lane..63]
    unsigned excl = run - s;      // sum over lanes > lane
    if (lane == 0) R.tot = run;   // total
    if (incl >= (unsigned)TOPK && excl < (unsigned)TOPK) {
      unsigned cum = excl;
      int jsel = 0;
      unsigned c_ge = 0;
#pragma unroll
      for (int j = 15; j >= 0; --j) {  // high bin -> low bin
        if (c_ge == 0 && cum + v[j] >= (unsigned)TOPK) { jsel = j; c_ge = cum + v[j]; }
        if (c_ge == 0) cum += v[j];
      }
      R.bin = HBASE + (unsigned)(lane * 16 + jsel);
      R.cge = c_ge;
    }
  }
}

// ---------------- zero histp + hists + meta (129 KB) ----------------
__global__ void __launch_bounds__(256) k_zero(unsigned* __restrict__ p) {
  p[blockIdx.x * 256 + threadIdx.x] = 0u;  // grid sized exactly to region
}

// ---------------- phase A: pobj keys + pobj histogram (8 MB read instead of 129) -------
__global__ void __launch_bounds__(256) k_pobj(const float* __restrict__ regs,
                                              unsigned* __restrict__ pkey,
                                              unsigned* __restrict__ histp) {
  int g = blockIdx.x * 256 + threadIdx.x;  // grid = BB*NN/256 = 1575 exactly
  float pobj = regs[(size_t)g * 5 + 4];
  unsigned key = flipKey(pobj);
  pkey[g] = key;
  if (pobj >= 0.05f)
    atomicAdd(&histp[(size_t)(g / NN) * HBINS + ((key >> 16) - HBASE)], 1u);
}

// ---------------- phase B: score rows in a pobj-bin range (cutoff inlined) -------------
// mode 0: lo = b1p (from histp; published to meta.b1p)
// mode 1: lo = b1c (from hists),  hi = meta.b1p (published by mode-0 launch)
// Union = {pk16 >= b1c} provably contains every possible top-TOPK row.
__global__ void __launch_bounds__(256) k_cand(const float* __restrict__ regs,
                                              const float* __restrict__ clses,
                                              const unsigned* __restrict__ pkey,
                                              const unsigned* __restrict__ cuthist,
                                              Meta* __restrict__ meta,
                                              unsigned* __restrict__ keys,
                                              float* __restrict__ ccs,
                                              int* __restrict__ preds,
                                              unsigned* __restrict__ hists, int mode) {
  __shared__ CutRes R;
  int img = blockIdx.x / BPI;
  int i = (blockIdx.x % BPI) * 256 + threadIdx.x;
  wave_cutoff(R, cuthist + (size_t)img * HBINS);
  __syncthreads();  // single barrier (replaces 17)
  unsigned cut = (R.tot < (unsigned)TOPK) ? (HBASE + 1) : R.bin;
  unsigned lo, hi;
  if (mode == 0) {
    lo = cut;
    hi = 0x10000u;
    if (threadIdx.x == 0 && (blockIdx.x % BPI) == 0) meta[img].b1p = cut;
  } else {
    lo = cut;
    hi = meta[img].b1p;  // published by mode-0 kernel (previous launch)
    if (threadIdx.x == 0 && (blockIdx.x % BPI) == 0) meta[img].b1c = cut;
  }
  if (i >= NN) return;
  size_t g = (size_t)img * NN + (size_t)i;
  unsigned pk = pkey[g];
  unsigned pk16 = pk >> 16;
  if (pk16 < lo || pk16 >= hi) {
    if (mode == 0) keys[g] = 0u;  // full coverage: unscored rows never pass compact
    return;
  }
  const float4* r4 = reinterpret_cast<const float4*>(clses + g * NCLS);
  float best = -1.0f;
  int bi = 0;
#pragma unroll
  for (int f = 0; f < 20; ++f) {
    float4 v = r4[f];
    int b0 = f * 4;
    if (v.x > best) { best = v.x; bi = b0 + 0; }
    if (v.y > best) { best = v.y; bi = b0 + 1; }
    if (v.z > best) { best = v.z; bi = b0 + 2; }
    if (v.w > best) { best = v.w; bi = b0 + 3; }
  }
  float pobj = unflipKey(pk);
  float sc = pobj * best;
  bool pass = (sc >= 0.05f);
  unsigned key = flipKey(pass ? sc : NEGV);
  keys[g] = key;
  ccs[g] = best;
  preds[g] = bi;
  if (pass) atomicAdd(&hists[(size_t)img * HBINS + ((key >> 16) - HBASE)], 1u);
}

// ---------------- compaction (final cutoff inlined; publishes b1/n_true) ----------------
__global__ void __launch_bounds__(256) k_compact(const float* __restrict__ regs,
                                                 const float* __restrict__ anchors,
                                                 const unsigned* __restrict__ keys,
                                                 const float* __restrict__ ccs,
                                                 const int* __restrict__ preds,
                                                 const unsigned* __restrict__ hists,
                                                 Meta* __restrict__ meta,
                                                 float* __restrict__ cand) {
  __shared__ CutRes R;
  const size_t S2 = (size_t)BB * CAND_CAP;
  int img = blockIdx.x / BPI;
  int i = (blockIdx.x % BPI) * 256 + threadIdx.x;
  wave_cutoff(R, hists + (size_t)img * HBINS);
  __syncthreads();
  unsigned b1, n_true;
  if (R.tot < (unsigned)TOPK) {
    b1 = HBASE + 1;
    n_true = R.tot;
  } else {
    b1 = R.bin;
    n_true = (R.cge > (unsigned)TOPK) ? (unsigned)TOPK : R.cge;
  }
  if (threadIdx.x == 0 && (blockIdx.x % BPI) == 0) {
    meta[img].b1 = b1;
    meta[img].n_true = n_true;  // consumed by k_rank/k_matrix/k_scan2 (later launches)
  }
  if (i >= NN) return;
  int lane = threadIdx.x & 63;
  unsigned long long lt = (1ull << lane) - 1ull;
  size_t g = (size_t)img * NN + (size_t)i;
  unsigned key = keys[g];
  bool take = (key >> 16) >= b1;
  unsigned long long mA = __ballot(take);
  if (!take) return;
  int leader = __builtin_ctzll(mA);
  unsigned base = 0;
  if (lane == leader) base = atomicAdd(&meta[img].cnt, (unsigned)__popcll(mA));
  base = __shfl(base, leader);
  unsigned pos = base + (unsigned)__popcll(mA & lt);
  if (pos >= CAND_CAP) return;
  const float* r = regs + g * 5;
  float d0 = r[0], d1 = r[1], d2 = r[2], d3 = r[3], obj = r[4];
  const float* a = anchors + (size_t)i * 4;
  float ax1 = a[0], ay1 = a[1], ax2 = a[2], ay2 = a[3];
  float aw = ax2 - ax1, ah = ay2 - ay1;
  float acx = (ax1 + ax2) * 0.5f, acy = (ay1 + ay2) * 0.5f;
  float cx = acx + d0 * aw, cy = acy + d1 * ah;
  float w = aw * expf(d2), h = ah * expf(d3);
  float hw = 0.5f * w, hh = 0.5f * h;
  float x1 = fminf(fmaxf(cx - hw, 0.0f), IMGSZ);
  float y1 = fminf(fmaxf(cy - hh, 0.0f), IMGSZ);
  float x2 = fminf(fmaxf(cx + hw, 0.0f), IMGSZ);
  float y2 = fminf(fmaxf(cy + hh, 0.0f), IMGSZ);
  size_t o = (size_t)img * CAND_CAP + pos;
  cand[0 * S2 + o] = x1;
  cand[1 * S2 + o] = y1;
  cand[2 * S2 + o] = x2;
  cand[3 * S2 + o] = y2;
  cand[4 * S2 + o] = obj;
  cand[5 * S2 + o] = ccs[g];
  cand[6 * S2 + o] = (float)preds[g];
  cand[7 * S2 + o] = unflipKey(key);
  reinterpret_cast<unsigned*>(cand + 8 * S2)[o] = (unsigned)i;
}

// ---------------- rank by counting: rank = #bigger 48-bit keys; scatter to rank space ----
__global__ void __launch_bounds__(256) k_rank(const float* __restrict__ cand,
                                              const Meta* __restrict__ meta,
                                              float* __restrict__ boxr,
                                              float4* __restrict__ payr0,
                                              float4* __restrict__ payr1) {
  const size_t S2 = (size_t)BB * CAND_CAP;
  const int NR = BB * RANKS;
  __shared__ unsigned long long kk[CAND_CAP];  // 16 KB
  int img = blockIdx.x >> 5;
  int part = blockIdx.x & 31;
  int tid = threadIdx.x;
  unsigned nload = meta[img].cnt;
  if (nload > CAND_CAP) nload = CAND_CAP;
  for (int i = tid; i < CAND_CAP; i += 256) {
    unsigned long long kv = 0ull;
    if (i < (int)nload) {
      float sc = cand[7 * S2 + (size_t)img * CAND_CAP + i];
      unsigned ai = reinterpret_cast<const unsigned*>(cand + 8 * S2)[(size_t)img * CAND_CAP + i];
      kv = ((unsigned long long)flipKey(sc) << 16) |
           (unsigned long long)((0x7FFFu - ai) & 0xFFFFu);  // unique via ai
    }
    kk[i] = kv;
  }
  __syncthreads();
  int slot = part * 64 + (tid >> 2);
  int qtr = tid & 3;
  unsigned long long myk = kk[slot];
  unsigned rank = 0;
  for (int q = qtr * 512; q < qtr * 512 + 512; ++q) rank += (kk[q] > myk) ? 1u : 0u;
  rank += (unsigned)__builtin_amdgcn_update_dpp(0, (int)rank, 0xB1, 0xF, 0xF, true);
  rank += (unsigned)__builtin_amdgcn_update_dpp(0, (int)rank, 0x4E, 0xF, 0xF, true);
  if (qtr == 0 && slot < (int)nload && rank < RANKS) {
    size_t o = (size_t)img * CAND_CAP + slot;
    float x1 = cand[0 * S2 + o], y1 = cand[1 * S2 + o];
    float x2 = cand[2 * S2 + o], y2 = cand[3 * S2 + o];
    float obj = cand[4 * S2 + o], cc = cand[5 * S2 + o];
    float cp = cand[6 * S2 + o], sc = cand[7 * S2 + o];
    float offv = cp * 4096.0f;
    float a1 = x1 + offv, b1v = y1 + offv, a2 = x2 + offv, b2v = y2 + offv;
    size_t ro = (size_t)img * RANKS + rank;
    boxr[0 * NR + ro] = a1;
    boxr[1 * NR + ro] = b1v;
    boxr[2 * NR + ro] = a2;
    boxr[3 * NR + ro] = b2v;
    boxr[4 * NR + ro] = (a2 - a1) * (b2v - b1v);
    payr0[ro] = make_float4(x1, y1, x2, y2);
    payr1[ro] = make_float4(obj, cc, cp, sc);
  }
}

// ---------------- suppression bit-matrix in rank space (parallel) ----------------
__global__ void __launch_bounds__(256) k_matrix(const float* __restrict__ boxr,
                                                const Meta* __restrict__ meta,
                                                unsigned long long* __restrict__ mat) {
  const int NR = BB * RANKS;
  __shared__ float sx1[RANKS], sy1[RANKS], sx2[RANKS], sy2[RANKS], sar[RANKS];  // 20 KB
  int img = blockIdx.x >> 6;
  int part = blockIdx.x & 63;
  int tid = threadIdx.x, lane = tid & 63, wid = tid >> 6;
  for (int i = tid; i < RANKS; i += 256) {
    int g = img * RANKS + i;
    sx1[i] = boxr[0 * NR + g];
    sy1[i] = boxr[1 * NR + g];
    sx2[i] = boxr[2 * NR + g];
    sy2[i] = boxr[3 * NR + g];
    sar[i] = boxr[4 * NR + g];
  }
  unsigned n = meta[img].n_true;
  __syncthreads();
#pragma unroll
  for (int rr = 0; rr < 4; ++rr) {
    int r = part * 16 + wid * 4 + rr;
    if (r >= (int)n) continue;  // wave-uniform
    float bx1 = sx1[r], by1 = sy1[r], bx2 = sx2[r], by2 = sy2[r], bA = sar[r];
    unsigned long long* rowp = mat + ((size_t)img * RANKS + r) * 16;
#pragma unroll
    for (int w2 = 0; w2 < 16; ++w2) {
      int c = w2 * 64 + lane;
      float lx = fmaxf(bx1, sx1[c]), ly = fmaxf(by1, sy1[c]);
      float rx = fminf(bx2, sx2[c]), ry = fminf(by2, sy2[c]);
      float iw = fmaxf(rx - lx, 0.f), ih = fmaxf(ry - ly, 0.f);
      float inter = iw * ih;
      float uu = bA + sar[c] - inter;
      float ss = fmaf(2.0f, inter, -uu);  // exact 2i-u (Sterbenz in decision region)
      float tt = uu * 0x1p-24f;           // RN(i/u)>0.5 <=> ss>tt
      bool sup = (uu > 0.f && ss > tt) || (c == r);
      unsigned long long b = __ballot(sup);
      if (lane == w2) rowp[w2] = b;
    }
  }
}

// ---------------- serial scan: 1024-thread staging, trivial chain ----------------
__global__ void __launch_bounds__(1024, 1) k_scan2(const unsigned long long* __restrict__ mat,
                                                   const Meta* __restrict__ meta,
                                                   const float4* __restrict__ payr0,
                                                   const float4* __restrict__ payr1,
                                                   float* __restrict__ out) {
  __shared__ unsigned long long smat[RANKS * 16];  // 128 KB
  __shared__ unsigned wins[MAXDET];
  __shared__ float4 lout4[MAXDET * 7 / 4];
  int img = blockIdx.x, tid = threadIdx.x, lane = tid & 63, wid = tid >> 6;
  const uint4* gm = reinterpret_cast<const uint4*>(mat + (size_t)img * RANKS * 16);
  uint4* sm4 = reinterpret_cast<uint4*>(smat);
  for (int i = tid; i < RANKS * 16 / 2; i += 1024) sm4[i] = gm[i];
  if (tid < MAXDET) wins[tid] = 0xFFFFFFFFu;
  unsigned n = meta[img].n_true;
  __syncthreads();
  if (wid == 0) {
    unsigned long long alive = 0ull;
    if (lane < 16) {
      int lo = lane * 64;
      alive = ((int)n >= lo + 64) ? ~0ull
                                  : (((int)n > lo) ? ((1ull << ((int)n - lo)) - 1ull) : 0ull);
    }
    for (int it = 0; it < MAXDET; ++it) {
      unsigned long long any = __ballot(alive != 0ull);
      if (any == 0ull) break;  // rest of rows zero via sentinel
      int f = __builtin_ctzll(any);
      unsigned long long w = __shfl(alive, f);
      int r = f * 64 + __builtin_ctzll(w);
      if (lane == 0) wins[it] = (unsigned)r;
      unsigned long long rowv = (lane < 16) ? smat[r * 16 + lane] : 0ull;
      alive &= ~rowv;  // diag bit clears the winner itself
    }
  }
  __syncthreads();
  if (tid < MAXDET) {
    unsigned r = wins[tid];
    float* row = reinterpret_cast<float*>(lout4) + tid * 7;
    if (r == 0xFFFFFFFFu) {
      row[0] = 0.f; row[1] = 0.f; row[2] = 0.f; row[3] = 0.f;
      row[4] = 0.f; row[5] = 0.f; row[6] = 0.f;
    } else {
      float4 p0 = payr0[(size_t)img * RANKS + r];
      float4 p1 = payr1[(size_t)img * RANKS + r];
      row[0] = p0.x; row[1] = p0.y; row[2] = p0.z; row[3] = p0.w;
      row[4] = p1.x; row[5] = p1.y; row[6] = p1.z;
    }
  }
  __syncthreads();
  float4* go4 = reinterpret_cast<float4*>(out + (size_t)img * MAXDET * 7);
  if (tid < MAXDET * 7 / 4) go4[tid] = lout4[tid];
}

// ---------------- launch (8 dispatches) ----------------
extern "C" void kernel_launch(void* const* d_in, const int* in_sizes, int n_in,
                              void* d_out, int out_size, void* d_ws, size_t ws_size,
                              hipStream_t stream) {
  const float* regs = (const float*)d_in[0];
  const float* clses = (const float*)d_in[1];
  const float* anchors = (const float*)d_in[2];
  float* out = (float*)d_out;
  char* ws = (char*)d_ws;

  constexpr size_t HISTP_OFF = 0;                      // 64 KB pobj hist
  constexpr size_t HISTS_OFF = 65536;                  // 64 KB score hist
  constexpr size_t META_OFF = 131072;                  // 1 KB
  constexpr size_t ZERO_BYTES = 132096;                // 129*1024: hists+meta only
  constexpr size_t KEYS_OFF = 132096;                  // fully written by k_cand mode 0
  constexpr size_t ARR_BYTES = (size_t)BB * NN * 4;    // 1,612,800
  constexpr size_t CCS_OFF = KEYS_OFF + ARR_BYTES;
  constexpr size_t PREDS_OFF = CCS_OFF + ARR_BYTES;
  constexpr size_t PKEY_OFF = PREDS_OFF + ARR_BYTES;
  constexpr size_t CAND_OFF = PKEY_OFF + ARR_BYTES;
  constexpr size_t CAND_BYTES = (size_t)9 * BB * CAND_CAP * 4;  // 1.18 MB
  constexpr size_t BOXR_OFF = CAND_OFF + CAND_BYTES;
  constexpr size_t BOXR_BYTES = (size_t)5 * BB * RANKS * 4;  // 320 KB
  constexpr size_t PAYR_OFF = BOXR_OFF + BOXR_BYTES;
  constexpr size_t PAYR_BYTES = (size_t)2 * BB * RANKS * 16;  // 512 KB
  constexpr size_t MAT_OFF = PAYR_OFF + PAYR_BYTES;
  // MAT: BB * RANKS * 16 u64 = 2 MB

  unsigned* histp = (unsigned*)(ws + HISTP_OFF);
  unsigned* hists = (unsigned*)(ws + HISTS_OFF);
  Meta* meta = (Meta*)(ws + META_OFF);
  unsigned* keys = (unsigned*)(ws + KEYS_OFF);
  float* ccs = (float*)(ws + CCS_OFF);
  int* preds = (int*)(ws + PREDS_OFF);
  unsigned* pkey = (unsigned*)(ws + PKEY_OFF);
  float* cand = (float*)(ws + CAND_OFF);
  float* boxr = (float*)(ws + BOXR_OFF);
  float4* payr0 = (float4*)(ws + PAYR_OFF);
  float4* payr1 = (float4*)(ws + PAYR_OFF + (size_t)BB * RANKS * 16);
  unsigned long long* mat = (unsigned long long*)(ws + MAT_OFF);

  // zero hists + meta every launch (keys covered by k_cand mode 0's full write)
  k_zero<<<(int)(ZERO_BYTES / 1024), 256, 0, stream>>>((unsigned*)ws);

  k_pobj<<<BB * NN / 256, 256, 0, stream>>>(regs, pkey, histp);
  k_cand<<<BB * BPI, 256, 0, stream>>>(regs, clses, pkey, histp, meta, keys, ccs, preds,
                                       hists, 0);
  k_cand<<<BB * BPI, 256, 0, stream>>>(regs, clses, pkey, hists, meta, keys, ccs, preds,
                                       hists, 1);
  k_compact<<<BB * BPI, 256, 0, stream>>>(regs, anchors, keys, ccs, preds, hists, meta, cand);
  k_rank<<<BB * 32, 256, 0, stream>>>(cand, meta, boxr, payr0, payr1);
  k_matrix<<<BB * 64, 256, 0, stream>>>(boxr, meta, mat);
  k_scan2<<<BB, 1024, 0, stream>>>(mat, meta, payr0, payr1, out);
}